// Round 2
// baseline (386.374 us; speedup 1.0000x reference)
//
#include <hip/hip_runtime.h>
#include <stdint.h>

typedef uint16_t u16;
typedef __bf16 bf16x8 __attribute__((ext_vector_type(8)));
typedef float f32x4 __attribute__((ext_vector_type(4)));

__device__ __forceinline__ u16 f2bf(float f) {
  union { float f; uint32_t u; } v; v.f = f;
  uint32_t u = v.u;
  u += 0x7FFFu + ((u >> 16) & 1u);   // round-to-nearest-even
  return (u16)(u >> 16);
}
__device__ __forceinline__ float bf2f(u16 h) {
  union { uint32_t u; float f; } v; v.u = ((uint32_t)h) << 16; return v.f;
}

// ---------------------------------------------------------------------------
// Both weight transposes in one launch (grid.z selects matrix).
// fp32 [R][C] -> bf16 [C][R]
// ---------------------------------------------------------------------------
__global__ void transpose_both(const float* __restrict__ w1, u16* __restrict__ w1t,
                               const float* __restrict__ w2, u16* __restrict__ w2t) {
  const float* in; u16* out; int R, C;
  if (blockIdx.z == 0) { in = w1; out = w1t; R = 1024; C = 512; }
  else {
    if (blockIdx.x >= 4 || blockIdx.y >= 16) return;   // block-uniform exit
    in = w2; out = w2t; R = 512; C = 128;
  }
  __shared__ float tile[32][33];
  int bx = blockIdx.x * 32, by = blockIdx.y * 32;
  int tx = threadIdx.x, ty = threadIdx.y;  // block (32,8)
  for (int i = 0; i < 32; i += 8)
    tile[ty + i][tx] = in[(size_t)(by + ty + i) * C + bx + tx];
  __syncthreads();
  for (int i = 0; i < 32; i += 8)
    out[(size_t)(bx + ty + i) * R + by + tx] = f2bf(tile[tx][ty + i]);
}

// ---------------------------------------------------------------------------
// GEMM1: h = PReLU(x @ w1 + b1)   x fp32 [8192][1024] (cast in staging),
// w1t bf16 [512][1024], out bf16 [8192][512]
// Tile 128x128x64, 256 threads = 4 waves, wave = 32 rows x 128 cols.
// (Reverted from the BM=32xBN=512 fused-LN shape: that geometry staged
//  0.065 B/MAC vs 0.031 here — 2.1x LDS-staging for the same MFMA work.)
// ---------------------------------------------------------------------------
#define BM 128
#define BN 128
#define BKT 64

__launch_bounds__(256)
__global__ void gemm1_kernel(const float* __restrict__ A,
                             const u16* __restrict__ Bt,
                             const float* __restrict__ bias,
                             const float* __restrict__ prelu_a,
                             u16* __restrict__ out) {
  const int N = 512, K = 1024;
  __shared__ u16 As[BM][BKT + 8];   // row stride 144 B (16B-aligned, 4-bank step)
  __shared__ u16 Bs[BN][BKT + 8];
  const int lane = threadIdx.x & 63, wave = threadIdx.x >> 6;
  const int row0 = blockIdx.x * BM, col0 = blockIdx.y * BN;

  f32x4 zero4 = {0.f, 0.f, 0.f, 0.f};
  f32x4 acc[2][8];
#pragma unroll
  for (int i = 0; i < 2; ++i)
#pragma unroll
    for (int j = 0; j < 8; ++j) acc[i][j] = zero4;

  for (int k0 = 0; k0 < K; k0 += BKT) {
#pragma unroll
    for (int s = 0; s < 4; ++s) {
      int c = threadIdx.x + s * 256;
      int r = c >> 3, kc = (c & 7) << 3;
      const float4* p = (const float4*)(A + (size_t)(row0 + r) * K + k0 + kc);
      float4 f0 = p[0], f1 = p[1];
      u16 tmp[8] = {f2bf(f0.x), f2bf(f0.y), f2bf(f0.z), f2bf(f0.w),
                    f2bf(f1.x), f2bf(f1.y), f2bf(f1.z), f2bf(f1.w)};
      *(uint4*)(&As[r][kc]) = *(uint4*)tmp;
      *(uint4*)(&Bs[r][kc]) = *(const uint4*)(Bt + (size_t)(col0 + r) * K + k0 + kc);
    }
    __syncthreads();
#pragma unroll
    for (int kk = 0; kk < BKT; kk += 32) {
      bf16x8 a[2], b[8];
#pragma unroll
      for (int i = 0; i < 2; ++i)
        a[i] = *(const bf16x8*)(&As[wave * 32 + i * 16 + (lane & 15)][kk + (lane >> 4) * 8]);
#pragma unroll
      for (int j = 0; j < 8; ++j)
        b[j] = *(const bf16x8*)(&Bs[j * 16 + (lane & 15)][kk + (lane >> 4) * 8]);
#pragma unroll
      for (int i = 0; i < 2; ++i)
#pragma unroll
        for (int j = 0; j < 8; ++j)
          acc[i][j] = __builtin_amdgcn_mfma_f32_16x16x32_bf16(a[i], b[j], acc[i][j], 0, 0, 0);
    }
    __syncthreads();
  }

  float ap = *prelu_a;
#pragma unroll
  for (int i = 0; i < 2; ++i)
#pragma unroll
    for (int r = 0; r < 4; ++r) {
      int row = row0 + wave * 32 + i * 16 + (lane >> 4) * 4 + r;
#pragma unroll
      for (int j = 0; j < 8; ++j) {
        int col = col0 + j * 16 + (lane & 15);
        float v = acc[i][j][r] + bias[col];
        v = v >= 0.f ? v : ap * v;
        out[(size_t)row * N + col] = f2bf(v);
      }
    }
}

// ---------------------------------------------------------------------------
// LayerNorm over 512 cols: one wave per row (64 lanes x 8 bf16)
// ---------------------------------------------------------------------------
__launch_bounds__(256)
__global__ void ln_kernel(const u16* __restrict__ h, const float* __restrict__ gamma,
                          const float* __restrict__ beta, u16* __restrict__ out) {
  int lane = threadIdx.x & 63, wave = threadIdx.x >> 6;
  int row = blockIdx.x * 4 + wave;
  uint4 raw = *(const uint4*)(h + (size_t)row * 512 + lane * 8);
  u16* up = (u16*)&raw;
  float v[8], s = 0.f, s2 = 0.f;
#pragma unroll
  for (int e = 0; e < 8; ++e) { v[e] = bf2f(up[e]); s += v[e]; s2 += v[e] * v[e]; }
  for (int m = 1; m < 64; m <<= 1) { s += __shfl_xor(s, m); s2 += __shfl_xor(s2, m); }
  float mu = s * (1.f / 512.f);
  float var = s2 * (1.f / 512.f) - mu * mu;
  float rstd = rsqrtf(var + 1e-6f);
  u16 o[8];
#pragma unroll
  for (int e = 0; e < 8; ++e) {
    int c = lane * 8 + e;
    o[e] = f2bf((v[e] - mu) * rstd * gamma[c] + beta[c]);
  }
  *(uint4*)(out + (size_t)row * 512 + lane * 8) = *(uint4*)o;
}

// ---------------------------------------------------------------------------
// GEMM2 + bias + row-normalize: z = hln @ w2 + b2 (fp32 -> d_out, NT store),
// zn = z / max(||z||,1e-8) (bf16 -> ws). BN=128 covers full out_dim.
// ---------------------------------------------------------------------------
__launch_bounds__(256)
__global__ void gemm2_kernel(const u16* __restrict__ A, const u16* __restrict__ Bt,
                             const float* __restrict__ bias,
                             float* __restrict__ z, u16* __restrict__ zn) {
  const int K = 512;
  __shared__ u16 As[BM][BKT + 8];
  __shared__ u16 Bs[BN][BKT + 8];
  const int lane = threadIdx.x & 63, wave = threadIdx.x >> 6;
  const int row0 = blockIdx.x * BM;

  f32x4 zero4 = {0.f, 0.f, 0.f, 0.f};
  f32x4 acc[2][8];
#pragma unroll
  for (int i = 0; i < 2; ++i)
#pragma unroll
    for (int j = 0; j < 8; ++j) acc[i][j] = zero4;

  const int r0 = threadIdx.x >> 3, kc0 = (threadIdx.x & 7) << 3;

  for (int k0 = 0; k0 < K; k0 += BKT) {
#pragma unroll
    for (int s = 0; s < 4; ++s) {
      int r = r0 + s * 32;
      *(uint4*)(&As[r][kc0]) = *(const uint4*)(A + (size_t)(row0 + r) * K + k0 + kc0);
      *(uint4*)(&Bs[r][kc0]) = *(const uint4*)(Bt + (size_t)r * K + k0 + kc0);
    }
    __syncthreads();
#pragma unroll
    for (int kk = 0; kk < BKT; kk += 32) {
      bf16x8 a[2], b[8];
#pragma unroll
      for (int i = 0; i < 2; ++i)
        a[i] = *(const bf16x8*)(&As[wave * 32 + i * 16 + (lane & 15)][kk + (lane >> 4) * 8]);
#pragma unroll
      for (int j = 0; j < 8; ++j)
        b[j] = *(const bf16x8*)(&Bs[j * 16 + (lane & 15)][kk + (lane >> 4) * 8]);
#pragma unroll
      for (int i = 0; i < 2; ++i)
#pragma unroll
        for (int j = 0; j < 8; ++j)
          acc[i][j] = __builtin_amdgcn_mfma_f32_16x16x32_bf16(a[i], b[j], acc[i][j], 0, 0, 0);
    }
    __syncthreads();
  }

#pragma unroll
  for (int i = 0; i < 2; ++i)
#pragma unroll
    for (int r = 0; r < 4; ++r) {
      int row = row0 + wave * 32 + i * 16 + (lane >> 4) * 4 + r;
      float vv[8], s = 0.f;
#pragma unroll
      for (int j = 0; j < 8; ++j) {
        int col = j * 16 + (lane & 15);
        float v = acc[i][j][r] + bias[col];
        vv[j] = v; s += v * v;
      }
      s += __shfl_xor(s, 1); s += __shfl_xor(s, 2);
      s += __shfl_xor(s, 4); s += __shfl_xor(s, 8);
      float inv = 1.f / fmaxf(sqrtf(s), 1e-8f);
#pragma unroll
      for (int j = 0; j < 8; ++j) {
        int col = j * 16 + (lane & 15);
        __builtin_nontemporal_store(vv[j], &z[(size_t)row * 128 + col]);
        zn[(size_t)row * 128 + col] = f2bf(vv[j] * inv);
      }
    }
}

// ---------------------------------------------------------------------------
// Gram: y = zn @ zn^T, zn bf16 [8192][128], y fp32 [8192][8192].
// K=128 fits LDS in ONE staging phase (69.6 KB): single barrier, no k0 loop.
// Output never re-read -> non-temporal stores.
// ---------------------------------------------------------------------------
__launch_bounds__(256)
__global__ void gram_kernel(const u16* __restrict__ Z, float* __restrict__ y) {
  const int K = 128, Bdim = 8192;
  __shared__ u16 As[128][K + 8];   // row stride 272 B
  __shared__ u16 Bs[128][K + 8];
  const int lane = threadIdx.x & 63, wave = threadIdx.x >> 6;
  const int row0 = blockIdx.x * 128, col0 = blockIdx.y * 128;

  f32x4 zero4 = {0.f, 0.f, 0.f, 0.f};
  f32x4 acc[2][8];
#pragma unroll
  for (int i = 0; i < 2; ++i)
#pragma unroll
    for (int j = 0; j < 8; ++j) acc[i][j] = zero4;

  const int r0 = threadIdx.x >> 4, kc0 = (threadIdx.x & 15) << 3;
#pragma unroll
  for (int s = 0; s < 8; ++s) {
    int r = r0 + s * 16;
    *(uint4*)(&As[r][kc0]) = *(const uint4*)(Z + (size_t)(row0 + r) * K + kc0);
    *(uint4*)(&Bs[r][kc0]) = *(const uint4*)(Z + (size_t)(col0 + r) * K + kc0);
  }
  __syncthreads();

#pragma unroll
  for (int kk = 0; kk < K; kk += 32) {
    bf16x8 a[2], b[8];
#pragma unroll
    for (int i = 0; i < 2; ++i)
      a[i] = *(const bf16x8*)(&As[wave * 32 + i * 16 + (lane & 15)][kk + (lane >> 4) * 8]);
#pragma unroll
    for (int j = 0; j < 8; ++j)
      b[j] = *(const bf16x8*)(&Bs[j * 16 + (lane & 15)][kk + (lane >> 4) * 8]);
#pragma unroll
    for (int i = 0; i < 2; ++i)
#pragma unroll
      for (int j = 0; j < 8; ++j)
        acc[i][j] = __builtin_amdgcn_mfma_f32_16x16x32_bf16(a[i], b[j], acc[i][j], 0, 0, 0);
  }

#pragma unroll
  for (int i = 0; i < 2; ++i)
#pragma unroll
    for (int r = 0; r < 4; ++r) {
      int row = row0 + wave * 32 + i * 16 + (lane >> 4) * 4 + r;
#pragma unroll
      for (int j = 0; j < 8; ++j) {
        int col = col0 + j * 16 + (lane & 15);
        __builtin_nontemporal_store(acc[i][j][r], &y[(size_t)row * Bdim + col]);
      }
    }
}

// ---------------------------------------------------------------------------
// Launch. Inputs: x, w1, b1, prelu_a, ln_gamma, ln_beta, w2, b2.
// d_out = [z (8192*128) | y_hat (8192*8192)] fp32.
// ws (bytes): w1t 1 MB @0, w2t 128 KB @1M, hact 8 MB, hln 8 MB, zn 2 MB.
// ---------------------------------------------------------------------------
extern "C" void kernel_launch(void* const* d_in, const int* in_sizes, int n_in,
                              void* d_out, int out_size, void* d_ws, size_t ws_size,
                              hipStream_t stream) {
  const float* x       = (const float*)d_in[0];
  const float* w1      = (const float*)d_in[1];
  const float* b1      = (const float*)d_in[2];
  const float* prelu_a = (const float*)d_in[3];
  const float* gamma   = (const float*)d_in[4];
  const float* beta    = (const float*)d_in[5];
  const float* w2      = (const float*)d_in[6];
  const float* b2      = (const float*)d_in[7];

  float* z_out = (float*)d_out;
  float* yhat  = z_out + (size_t)8192 * 128;

  char* ws = (char*)d_ws;
  u16* w1t  = (u16*)(ws);                                        // [512][1024]  1 MB
  u16* w2t  = (u16*)(ws + (1u << 20));                           // [128][512]   128 KB
  u16* hact = (u16*)(ws + (1u << 20) + (1u << 17));              // [8192][512]  8 MB
  u16* hln  = (u16*)(ws + (1u << 20) + (1u << 17) + (8u << 20)); // [8192][512]  8 MB
  u16* zn   = (u16*)(ws + (1u << 20) + (1u << 17) + (16u << 20)); // [8192][128] 2 MB

  transpose_both<<<dim3(16, 32, 2), dim3(32, 8), 0, stream>>>(w1, w1t, w2, w2t);
  gemm1_kernel<<<dim3(64, 4), 256, 0, stream>>>(x, w1t, b1, prelu_a, hact);
  ln_kernel<<<2048, 256, 0, stream>>>(hact, gamma, beta, hln);
  gemm2_kernel<<<64, 256, 0, stream>>>(hln, w2t, b2, z_out, zn);
  gram_kernel<<<dim3(64, 64), 256, 0, stream>>>(zn, yhat);
}

// Round 3
// 365.764 us; speedup vs baseline: 1.0563x; 1.0563x over previous
//
#include <hip/hip_runtime.h>
#include <stdint.h>

typedef uint16_t u16;
typedef __bf16 bf16x8 __attribute__((ext_vector_type(8)));
typedef float f32x4 __attribute__((ext_vector_type(4)));

__device__ __forceinline__ u16 f2bf(float f) {
  union { float f; uint32_t u; } v; v.f = f;
  uint32_t u = v.u;
  u += 0x7FFFu + ((u >> 16) & 1u);   // round-to-nearest-even
  return (u16)(u >> 16);
}
__device__ __forceinline__ float bf2f(u16 h) {
  union { uint32_t u; float f; } v; v.u = ((uint32_t)h) << 16; return v.f;
}

// ---------------------------------------------------------------------------
// Both weight transposes in one launch (grid.z selects matrix).
// fp32 [R][C] -> bf16 [C][R]
// ---------------------------------------------------------------------------
__global__ void transpose_both(const float* __restrict__ w1, u16* __restrict__ w1t,
                               const float* __restrict__ w2, u16* __restrict__ w2t) {
  const float* in; u16* out; int R, C;
  if (blockIdx.z == 0) { in = w1; out = w1t; R = 1024; C = 512; }
  else {
    if (blockIdx.x >= 4 || blockIdx.y >= 16) return;   // block-uniform exit
    in = w2; out = w2t; R = 512; C = 128;
  }
  __shared__ float tile[32][33];
  int bx = blockIdx.x * 32, by = blockIdx.y * 32;
  int tx = threadIdx.x, ty = threadIdx.y;  // block (32,8)
  for (int i = 0; i < 32; i += 8)
    tile[ty + i][tx] = in[(size_t)(by + ty + i) * C + bx + tx];
  __syncthreads();
  for (int i = 0; i < 32; i += 8)
    out[(size_t)(bx + ty + i) * R + by + tx] = f2bf(tile[tx][ty + i]);
}

// ---------------------------------------------------------------------------
// GEMM1: h = PReLU(x @ w1 + b1)   x fp32 [8192][1024] (cast in staging),
// w1t bf16 [512][1024], out bf16 [8192][512]
// Tile 128x128x64, 256 threads = 4 waves, wave = 32 rows x 128 cols.
// ---------------------------------------------------------------------------
#define BM 128
#define BN 128
#define BKT 64

__launch_bounds__(256)
__global__ void gemm1_kernel(const float* __restrict__ A,
                             const u16* __restrict__ Bt,
                             const float* __restrict__ bias,
                             const float* __restrict__ prelu_a,
                             u16* __restrict__ out) {
  const int N = 512, K = 1024;
  __shared__ u16 As[BM][BKT + 8];   // row stride 144 B (16B-aligned, 4-bank step)
  __shared__ u16 Bs[BN][BKT + 8];
  const int lane = threadIdx.x & 63, wave = threadIdx.x >> 6;
  const int row0 = blockIdx.x * BM, col0 = blockIdx.y * BN;

  f32x4 zero4 = {0.f, 0.f, 0.f, 0.f};
  f32x4 acc[2][8];
#pragma unroll
  for (int i = 0; i < 2; ++i)
#pragma unroll
    for (int j = 0; j < 8; ++j) acc[i][j] = zero4;

  for (int k0 = 0; k0 < K; k0 += BKT) {
#pragma unroll
    for (int s = 0; s < 4; ++s) {
      int c = threadIdx.x + s * 256;
      int r = c >> 3, kc = (c & 7) << 3;
      const float4* p = (const float4*)(A + (size_t)(row0 + r) * K + k0 + kc);
      float4 f0 = p[0], f1 = p[1];
      u16 tmp[8] = {f2bf(f0.x), f2bf(f0.y), f2bf(f0.z), f2bf(f0.w),
                    f2bf(f1.x), f2bf(f1.y), f2bf(f1.z), f2bf(f1.w)};
      *(uint4*)(&As[r][kc]) = *(uint4*)tmp;
      *(uint4*)(&Bs[r][kc]) = *(const uint4*)(Bt + (size_t)(col0 + r) * K + k0 + kc);
    }
    __syncthreads();
#pragma unroll
    for (int kk = 0; kk < BKT; kk += 32) {
      bf16x8 a[2], b[8];
#pragma unroll
      for (int i = 0; i < 2; ++i)
        a[i] = *(const bf16x8*)(&As[wave * 32 + i * 16 + (lane & 15)][kk + (lane >> 4) * 8]);
#pragma unroll
      for (int j = 0; j < 8; ++j)
        b[j] = *(const bf16x8*)(&Bs[j * 16 + (lane & 15)][kk + (lane >> 4) * 8]);
#pragma unroll
      for (int i = 0; i < 2; ++i)
#pragma unroll
        for (int j = 0; j < 8; ++j)
          acc[i][j] = __builtin_amdgcn_mfma_f32_16x16x32_bf16(a[i], b[j], acc[i][j], 0, 0, 0);
    }
    __syncthreads();
  }

  float ap = *prelu_a;
#pragma unroll
  for (int i = 0; i < 2; ++i)
#pragma unroll
    for (int r = 0; r < 4; ++r) {
      int row = row0 + wave * 32 + i * 16 + (lane >> 4) * 4 + r;
#pragma unroll
      for (int j = 0; j < 8; ++j) {
        int col = col0 + j * 16 + (lane & 15);
        float v = acc[i][j][r] + bias[col];
        v = v >= 0.f ? v : ap * v;
        out[(size_t)row * N + col] = f2bf(v);
      }
    }
}

// ---------------------------------------------------------------------------
// LayerNorm over 512 cols: one wave per row (64 lanes x 8 bf16)
// ---------------------------------------------------------------------------
__launch_bounds__(256)
__global__ void ln_kernel(const u16* __restrict__ h, const float* __restrict__ gamma,
                          const float* __restrict__ beta, u16* __restrict__ out) {
  int lane = threadIdx.x & 63, wave = threadIdx.x >> 6;
  int row = blockIdx.x * 4 + wave;
  uint4 raw = *(const uint4*)(h + (size_t)row * 512 + lane * 8);
  u16* up = (u16*)&raw;
  float v[8], s = 0.f, s2 = 0.f;
#pragma unroll
  for (int e = 0; e < 8; ++e) { v[e] = bf2f(up[e]); s += v[e]; s2 += v[e] * v[e]; }
  for (int m = 1; m < 64; m <<= 1) { s += __shfl_xor(s, m); s2 += __shfl_xor(s2, m); }
  float mu = s * (1.f / 512.f);
  float var = s2 * (1.f / 512.f) - mu * mu;
  float rstd = rsqrtf(var + 1e-6f);
  u16 o[8];
#pragma unroll
  for (int e = 0; e < 8; ++e) {
    int c = lane * 8 + e;
    o[e] = f2bf((v[e] - mu) * rstd * gamma[c] + beta[c]);
  }
  *(uint4*)(out + (size_t)row * 512 + lane * 8) = *(uint4*)o;
}

// ---------------------------------------------------------------------------
// GEMM2 + bias + row-normalize: z = hln @ w2 + b2 (fp32 -> d_out),
// zn = z / max(||z||,1e-8) (bf16 -> ws).  BN=128 covers full out_dim, so the
// row norm reduces in-register: over j locally + xor-shuffle over the 16
// lanes of the accumulator quad.
// ---------------------------------------------------------------------------
__launch_bounds__(256)
__global__ void gemm2_kernel(const u16* __restrict__ A, const u16* __restrict__ Bt,
                             const float* __restrict__ bias,
                             float* __restrict__ z, u16* __restrict__ zn) {
  const int K = 512;
  __shared__ u16 As[BM][BKT + 8];
  __shared__ u16 Bs[BN][BKT + 8];
  const int lane = threadIdx.x & 63, wave = threadIdx.x >> 6;
  const int row0 = blockIdx.x * BM;

  f32x4 zero4 = {0.f, 0.f, 0.f, 0.f};
  f32x4 acc[2][8];
#pragma unroll
  for (int i = 0; i < 2; ++i)
#pragma unroll
    for (int j = 0; j < 8; ++j) acc[i][j] = zero4;

  const int r0 = threadIdx.x >> 3, kc0 = (threadIdx.x & 7) << 3;

  for (int k0 = 0; k0 < K; k0 += BKT) {
#pragma unroll
    for (int s = 0; s < 4; ++s) {
      int r = r0 + s * 32;
      *(uint4*)(&As[r][kc0]) = *(const uint4*)(A + (size_t)(row0 + r) * K + k0 + kc0);
      *(uint4*)(&Bs[r][kc0]) = *(const uint4*)(Bt + (size_t)r * K + k0 + kc0);
    }
    __syncthreads();
#pragma unroll
    for (int kk = 0; kk < BKT; kk += 32) {
      bf16x8 a[2], b[8];
#pragma unroll
      for (int i = 0; i < 2; ++i)
        a[i] = *(const bf16x8*)(&As[wave * 32 + i * 16 + (lane & 15)][kk + (lane >> 4) * 8]);
#pragma unroll
      for (int j = 0; j < 8; ++j)
        b[j] = *(const bf16x8*)(&Bs[j * 16 + (lane & 15)][kk + (lane >> 4) * 8]);
#pragma unroll
      for (int i = 0; i < 2; ++i)
#pragma unroll
        for (int j = 0; j < 8; ++j)
          acc[i][j] = __builtin_amdgcn_mfma_f32_16x16x32_bf16(a[i], b[j], acc[i][j], 0, 0, 0);
    }
    __syncthreads();
  }

#pragma unroll
  for (int i = 0; i < 2; ++i)
#pragma unroll
    for (int r = 0; r < 4; ++r) {
      int row = row0 + wave * 32 + i * 16 + (lane >> 4) * 4 + r;
      float vv[8], s = 0.f;
#pragma unroll
      for (int j = 0; j < 8; ++j) {
        int col = j * 16 + (lane & 15);
        float v = acc[i][j][r] + bias[col];
        vv[j] = v; s += v * v;
      }
      s += __shfl_xor(s, 1); s += __shfl_xor(s, 2);
      s += __shfl_xor(s, 4); s += __shfl_xor(s, 8);
      float inv = 1.f / fmaxf(sqrtf(s), 1e-8f);
#pragma unroll
      for (int j = 0; j < 8; ++j) {
        int col = j * 16 + (lane & 15);
        z[(size_t)row * 128 + col] = vv[j];
        zn[(size_t)row * 128 + col] = f2bf(vv[j] * inv);
      }
    }
}

// ---------------------------------------------------------------------------
// Gram: y = zn @ zn^T, zn bf16 [8192][128], y fp32 [8192][8192].
// Round-0 form restored: double-staged k0 loop, 36.9 KB LDS (4 blocks/CU),
// NORMAL stores (NT stores + 69.6 KB single-stage were the R1/R2 regression
// suspects: 268 MB write losing L2 write-combining + half the occupancy).
// ---------------------------------------------------------------------------
__launch_bounds__(256)
__global__ void gram_kernel(const u16* __restrict__ Z, float* __restrict__ y) {
  const int K = 128, Bdim = 8192;
  __shared__ u16 As[BM][BKT + 8];
  __shared__ u16 Bs[BN][BKT + 8];
  const int lane = threadIdx.x & 63, wave = threadIdx.x >> 6;
  const int row0 = blockIdx.x * BM, col0 = blockIdx.y * BN;

  f32x4 zero4 = {0.f, 0.f, 0.f, 0.f};
  f32x4 acc[2][8];
#pragma unroll
  for (int i = 0; i < 2; ++i)
#pragma unroll
    for (int j = 0; j < 8; ++j) acc[i][j] = zero4;

  for (int k0 = 0; k0 < K; k0 += BKT) {
#pragma unroll
    for (int s = 0; s < 4; ++s) {
      int c = threadIdx.x + s * 256;
      int r = c >> 3, kc = (c & 7) << 3;
      *(uint4*)(&As[r][kc]) = *(const uint4*)(Z + (size_t)(row0 + r) * K + k0 + kc);
      *(uint4*)(&Bs[r][kc]) = *(const uint4*)(Z + (size_t)(col0 + r) * K + k0 + kc);
    }
    __syncthreads();
#pragma unroll
    for (int kk = 0; kk < BKT; kk += 32) {
      bf16x8 a[2], b[8];
#pragma unroll
      for (int i = 0; i < 2; ++i)
        a[i] = *(const bf16x8*)(&As[wave * 32 + i * 16 + (lane & 15)][kk + (lane >> 4) * 8]);
#pragma unroll
      for (int j = 0; j < 8; ++j)
        b[j] = *(const bf16x8*)(&Bs[j * 16 + (lane & 15)][kk + (lane >> 4) * 8]);
#pragma unroll
      for (int i = 0; i < 2; ++i)
#pragma unroll
        for (int j = 0; j < 8; ++j)
          acc[i][j] = __builtin_amdgcn_mfma_f32_16x16x32_bf16(a[i], b[j], acc[i][j], 0, 0, 0);
    }
    __syncthreads();
  }

#pragma unroll
  for (int i = 0; i < 2; ++i)
#pragma unroll
    for (int r = 0; r < 4; ++r) {
      int row = row0 + wave * 32 + i * 16 + (lane >> 4) * 4 + r;
#pragma unroll
      for (int j = 0; j < 8; ++j) {
        int col = col0 + j * 16 + (lane & 15);
        y[(size_t)row * Bdim + col] = acc[i][j][r];
      }
    }
}

// ---------------------------------------------------------------------------
// Launch. Inputs: x, w1, b1, prelu_a, ln_gamma, ln_beta, w2, b2.
// d_out = [z (8192*128) | y_hat (8192*8192)] fp32.
// ws (bytes): w1t 1 MB @0, w2t 128 KB @1M, hact 8 MB, hln 8 MB, zn 2 MB.
// ---------------------------------------------------------------------------
extern "C" void kernel_launch(void* const* d_in, const int* in_sizes, int n_in,
                              void* d_out, int out_size, void* d_ws, size_t ws_size,
                              hipStream_t stream) {
  const float* x       = (const float*)d_in[0];
  const float* w1      = (const float*)d_in[1];
  const float* b1      = (const float*)d_in[2];
  const float* prelu_a = (const float*)d_in[3];
  const float* gamma   = (const float*)d_in[4];
  const float* beta    = (const float*)d_in[5];
  const float* w2      = (const float*)d_in[6];
  const float* b2      = (const float*)d_in[7];

  float* z_out = (float*)d_out;
  float* yhat  = z_out + (size_t)8192 * 128;

  char* ws = (char*)d_ws;
  u16* w1t  = (u16*)(ws);                                        // [512][1024]  1 MB
  u16* w2t  = (u16*)(ws + (1u << 20));                           // [128][512]   128 KB
  u16* hact = (u16*)(ws + (1u << 20) + (1u << 17));              // [8192][512]  8 MB
  u16* hln  = (u16*)(ws + (1u << 20) + (1u << 17) + (8u << 20)); // [8192][512]  8 MB
  u16* zn   = (u16*)(ws + (1u << 20) + (1u << 17) + (16u << 20)); // [8192][128] 2 MB

  transpose_both<<<dim3(16, 32, 2), dim3(32, 8), 0, stream>>>(w1, w1t, w2, w2t);
  gemm1_kernel<<<dim3(64, 4), 256, 0, stream>>>(x, w1t, b1, prelu_a, hact);
  ln_kernel<<<2048, 256, 0, stream>>>(hact, gamma, beta, hln);
  gemm2_kernel<<<64, 256, 0, stream>>>(hln, w2t, b2, z_out, zn);
  gram_kernel<<<dim3(64, 64), 256, 0, stream>>>(zn, yhat);
}

// Round 4
// 362.632 us; speedup vs baseline: 1.0655x; 1.0086x over previous
//
#include <hip/hip_runtime.h>
#include <stdint.h>

typedef uint16_t u16;
typedef __bf16 bf16x8 __attribute__((ext_vector_type(8)));
typedef float f32x4 __attribute__((ext_vector_type(4)));

__device__ __forceinline__ u16 f2bf(float f) {
  union { float f; uint32_t u; } v; v.f = f;
  uint32_t u = v.u;
  u += 0x7FFFu + ((u >> 16) & 1u);   // round-to-nearest-even
  return (u16)(u >> 16);
}
__device__ __forceinline__ float bf2f(u16 h) {
  union { uint32_t u; float f; } v; v.u = ((uint32_t)h) << 16; return v.f;
}

// ---------------------------------------------------------------------------
// Both weight transposes in one launch (grid.z selects matrix).
// fp32 [R][C] -> bf16 [C][R]
// ---------------------------------------------------------------------------
__global__ void transpose_both(const float* __restrict__ w1, u16* __restrict__ w1t,
                               const float* __restrict__ w2, u16* __restrict__ w2t) {
  const float* in; u16* out; int R, C;
  if (blockIdx.z == 0) { in = w1; out = w1t; R = 1024; C = 512; }
  else {
    if (blockIdx.x >= 4 || blockIdx.y >= 16) return;   // block-uniform exit
    in = w2; out = w2t; R = 512; C = 128;
  }
  __shared__ float tile[32][33];
  int bx = blockIdx.x * 32, by = blockIdx.y * 32;
  int tx = threadIdx.x, ty = threadIdx.y;  // block (32,8)
  for (int i = 0; i < 32; i += 8)
    tile[ty + i][tx] = in[(size_t)(by + ty + i) * C + bx + tx];
  __syncthreads();
  for (int i = 0; i < 32; i += 8)
    out[(size_t)(bx + ty + i) * R + by + tx] = f2bf(tile[tx][ty + i]);
}

// ---------------------------------------------------------------------------
// GEMM1: h = PReLU(x @ w1 + b1)   x fp32 [8192][1024] (cast in staging),
// w1t bf16 [512][1024], out bf16 [8192][512]
// Tile 64x128x64, grid (128,4) = 512 blocks = 2 blocks/CU (was 256 = 1/CU:
// 1 wave/SIMD left the stage+barrier drain fully exposed — m233/m114).
// 4 waves, wave = 16 rows x 128 cols.
// ---------------------------------------------------------------------------
#define BKT 64

__launch_bounds__(256)
__global__ void gemm1_kernel(const float* __restrict__ A,
                             const u16* __restrict__ Bt,
                             const float* __restrict__ bias,
                             const float* __restrict__ prelu_a,
                             u16* __restrict__ out) {
  const int N = 512, K = 1024;
  __shared__ u16 As[64][BKT + 8];    // 9.2 KB
  __shared__ u16 Bs[128][BKT + 8];   // 18.4 KB
  const int lane = threadIdx.x & 63, wave = threadIdx.x >> 6;
  const int row0 = blockIdx.x * 64, col0 = blockIdx.y * 128;

  f32x4 zero4 = {0.f, 0.f, 0.f, 0.f};
  f32x4 acc[8];
#pragma unroll
  for (int j = 0; j < 8; ++j) acc[j] = zero4;

  for (int k0 = 0; k0 < K; k0 += BKT) {
    // A panel: 64 rows x 64 k, fp32->bf16 cast; 2 chunks/thread
#pragma unroll
    for (int s = 0; s < 2; ++s) {
      int c = threadIdx.x + s * 256;
      int r = c >> 3, kc = (c & 7) << 3;
      const float4* p = (const float4*)(A + (size_t)(row0 + r) * K + k0 + kc);
      float4 f0 = p[0], f1 = p[1];
      u16 tmp[8] = {f2bf(f0.x), f2bf(f0.y), f2bf(f0.z), f2bf(f0.w),
                    f2bf(f1.x), f2bf(f1.y), f2bf(f1.z), f2bf(f1.w)};
      *(uint4*)(&As[r][kc]) = *(uint4*)tmp;
    }
    // B panel: 128 rows x 64 k bf16; 4 chunks/thread
#pragma unroll
    for (int s = 0; s < 4; ++s) {
      int c = threadIdx.x + s * 256;
      int r = c >> 3, kc = (c & 7) << 3;
      *(uint4*)(&Bs[r][kc]) = *(const uint4*)(Bt + (size_t)(col0 + r) * K + k0 + kc);
    }
    __syncthreads();
#pragma unroll
    for (int kk = 0; kk < BKT; kk += 32) {
      bf16x8 a, b[8];
      a = *(const bf16x8*)(&As[wave * 16 + (lane & 15)][kk + (lane >> 4) * 8]);
#pragma unroll
      for (int j = 0; j < 8; ++j)
        b[j] = *(const bf16x8*)(&Bs[j * 16 + (lane & 15)][kk + (lane >> 4) * 8]);
#pragma unroll
      for (int j = 0; j < 8; ++j)
        acc[j] = __builtin_amdgcn_mfma_f32_16x16x32_bf16(a, b[j], acc[j], 0, 0, 0);
    }
    __syncthreads();
  }

  float ap = *prelu_a;
#pragma unroll
  for (int r = 0; r < 4; ++r) {
    int row = row0 + wave * 16 + (lane >> 4) * 4 + r;
#pragma unroll
    for (int j = 0; j < 8; ++j) {
      int col = col0 + j * 16 + (lane & 15);
      float v = acc[j][r] + bias[col];
      v = v >= 0.f ? v : ap * v;
      out[(size_t)row * N + col] = f2bf(v);
    }
  }
}

// ---------------------------------------------------------------------------
// LayerNorm over 512 cols: one wave per row (64 lanes x 8 bf16)
// ---------------------------------------------------------------------------
__launch_bounds__(256)
__global__ void ln_kernel(const u16* __restrict__ h, const float* __restrict__ gamma,
                          const float* __restrict__ beta, u16* __restrict__ out) {
  int lane = threadIdx.x & 63, wave = threadIdx.x >> 6;
  int row = blockIdx.x * 4 + wave;
  uint4 raw = *(const uint4*)(h + (size_t)row * 512 + lane * 8);
  u16* up = (u16*)&raw;
  float v[8], s = 0.f, s2 = 0.f;
#pragma unroll
  for (int e = 0; e < 8; ++e) { v[e] = bf2f(up[e]); s += v[e]; s2 += v[e] * v[e]; }
  for (int m = 1; m < 64; m <<= 1) { s += __shfl_xor(s, m); s2 += __shfl_xor(s2, m); }
  float mu = s * (1.f / 512.f);
  float var = s2 * (1.f / 512.f) - mu * mu;
  float rstd = rsqrtf(var + 1e-6f);
  u16 o[8];
#pragma unroll
  for (int e = 0; e < 8; ++e) {
    int c = lane * 8 + e;
    o[e] = f2bf((v[e] - mu) * rstd * gamma[c] + beta[c]);
  }
  *(uint4*)(out + (size_t)row * 512 + lane * 8) = *(uint4*)o;
}

// ---------------------------------------------------------------------------
// GEMM2 + bias + row-normalize: z = hln @ w2 + b2 (fp32 -> d_out),
// zn = z / max(||z||,1e-8) (bf16 -> ws).
// BM=32, grid 256 (all CUs busy; was 64 blocks = 3/4 machine idle).
// 4 waves in 2x2 split: wave (wr,wc) owns rows wr*16.. x cols wc*64..
// Row ||z||^2: in-reg over j + 16-lane xor (half-row) + LDS exchange of the
// two wc halves.
// ---------------------------------------------------------------------------
__launch_bounds__(256)
__global__ void gemm2_kernel(const u16* __restrict__ A, const u16* __restrict__ Bt,
                             const float* __restrict__ bias,
                             float* __restrict__ z, u16* __restrict__ zn) {
  const int K = 512;
  __shared__ u16 As[32][BKT + 8];    // 4.6 KB
  __shared__ u16 Bs[128][BKT + 8];   // 18.4 KB
  __shared__ float hsum[32][2];      // per-row half sums
  const int lane = threadIdx.x & 63, wave = threadIdx.x >> 6;
  const int wr = wave >> 1, wc = wave & 1;
  const int row0 = blockIdx.x * 32;

  f32x4 zero4 = {0.f, 0.f, 0.f, 0.f};
  f32x4 acc[4];
#pragma unroll
  for (int j = 0; j < 4; ++j) acc[j] = zero4;

  for (int k0 = 0; k0 < K; k0 += BKT) {
    {  // A panel: 32 rows, 1 chunk/thread
      int r = threadIdx.x >> 3, kc = (threadIdx.x & 7) << 3;
      *(uint4*)(&As[r][kc]) = *(const uint4*)(A + (size_t)(row0 + r) * K + k0 + kc);
    }
#pragma unroll
    for (int s = 0; s < 4; ++s) {   // B panel: 128 rows
      int c = threadIdx.x + s * 256;
      int r = c >> 3, kc = (c & 7) << 3;
      *(uint4*)(&Bs[r][kc]) = *(const uint4*)(Bt + (size_t)r * K + k0 + kc);
    }
    __syncthreads();
#pragma unroll
    for (int kk = 0; kk < BKT; kk += 32) {
      bf16x8 a, b[4];
      a = *(const bf16x8*)(&As[wr * 16 + (lane & 15)][kk + (lane >> 4) * 8]);
#pragma unroll
      for (int j = 0; j < 4; ++j)
        b[j] = *(const bf16x8*)(&Bs[wc * 64 + j * 16 + (lane & 15)][kk + (lane >> 4) * 8]);
#pragma unroll
      for (int j = 0; j < 4; ++j)
        acc[j] = __builtin_amdgcn_mfma_f32_16x16x32_bf16(a, b[j], acc[j], 0, 0, 0);
    }
    __syncthreads();
  }

  // epilogue: bias, half-row sumsq, cross-wave exchange, normalize, store
  float vv[4][4];   // [r][j]
#pragma unroll
  for (int r = 0; r < 4; ++r) {
    float s = 0.f;
#pragma unroll
    for (int j = 0; j < 4; ++j) {
      int col = wc * 64 + j * 16 + (lane & 15);
      float v = acc[j][r] + bias[col];
      vv[r][j] = v; s += v * v;
    }
    s += __shfl_xor(s, 1); s += __shfl_xor(s, 2);
    s += __shfl_xor(s, 4); s += __shfl_xor(s, 8);
    if ((lane & 15) == 0) {
      int rloc = wr * 16 + (lane >> 4) * 4 + r;
      hsum[rloc][wc] = s;
    }
  }
  __syncthreads();
#pragma unroll
  for (int r = 0; r < 4; ++r) {
    int rloc = wr * 16 + (lane >> 4) * 4 + r;
    float s = hsum[rloc][0] + hsum[rloc][1];
    float inv = 1.f / fmaxf(sqrtf(s), 1e-8f);
    int row = row0 + rloc;
#pragma unroll
    for (int j = 0; j < 4; ++j) {
      int col = wc * 64 + j * 16 + (lane & 15);
      z[(size_t)row * 128 + col] = vv[r][j];
      zn[(size_t)row * 128 + col] = f2bf(vv[r][j] * inv);
    }
  }
}

// ---------------------------------------------------------------------------
// Gram: y = zn @ zn^T, zn bf16 [8192][128], y fp32 [8192][8192].
// Round-0 form: double-staged k0 loop, 36.9 KB LDS (4 blocks/CU), normal
// stores. (NT stores + single-stage 69.6 KB were a +19 us regression.)
// ---------------------------------------------------------------------------
#define GBM 128
#define GBN 128

__launch_bounds__(256)
__global__ void gram_kernel(const u16* __restrict__ Z, float* __restrict__ y) {
  const int K = 128, Bdim = 8192;
  __shared__ u16 As[GBM][BKT + 8];
  __shared__ u16 Bs[GBN][BKT + 8];
  const int lane = threadIdx.x & 63, wave = threadIdx.x >> 6;
  const int row0 = blockIdx.x * GBM, col0 = blockIdx.y * GBN;

  f32x4 zero4 = {0.f, 0.f, 0.f, 0.f};
  f32x4 acc[2][8];
#pragma unroll
  for (int i = 0; i < 2; ++i)
#pragma unroll
    for (int j = 0; j < 8; ++j) acc[i][j] = zero4;

  for (int k0 = 0; k0 < K; k0 += BKT) {
#pragma unroll
    for (int s = 0; s < 4; ++s) {
      int c = threadIdx.x + s * 256;
      int r = c >> 3, kc = (c & 7) << 3;
      *(uint4*)(&As[r][kc]) = *(const uint4*)(Z + (size_t)(row0 + r) * K + k0 + kc);
      *(uint4*)(&Bs[r][kc]) = *(const uint4*)(Z + (size_t)(col0 + r) * K + k0 + kc);
    }
    __syncthreads();
#pragma unroll
    for (int kk = 0; kk < BKT; kk += 32) {
      bf16x8 a[2], b[8];
#pragma unroll
      for (int i = 0; i < 2; ++i)
        a[i] = *(const bf16x8*)(&As[wave * 32 + i * 16 + (lane & 15)][kk + (lane >> 4) * 8]);
#pragma unroll
      for (int j = 0; j < 8; ++j)
        b[j] = *(const bf16x8*)(&Bs[j * 16 + (lane & 15)][kk + (lane >> 4) * 8]);
#pragma unroll
      for (int i = 0; i < 2; ++i)
#pragma unroll
        for (int j = 0; j < 8; ++j)
          acc[i][j] = __builtin_amdgcn_mfma_f32_16x16x32_bf16(a[i], b[j], acc[i][j], 0, 0, 0);
    }
    __syncthreads();
  }

#pragma unroll
  for (int i = 0; i < 2; ++i)
#pragma unroll
    for (int r = 0; r < 4; ++r) {
      int row = row0 + wave * 32 + i * 16 + (lane >> 4) * 4 + r;
#pragma unroll
      for (int j = 0; j < 8; ++j) {
        int col = col0 + j * 16 + (lane & 15);
        y[(size_t)row * Bdim + col] = acc[i][j][r];
      }
    }
}

// ---------------------------------------------------------------------------
// Launch. Inputs: x, w1, b1, prelu_a, ln_gamma, ln_beta, w2, b2.
// d_out = [z (8192*128) | y_hat (8192*8192)] fp32.
// ws (bytes): w1t 1 MB @0, w2t 128 KB @1M, hact 8 MB, hln 8 MB, zn 2 MB.
// ---------------------------------------------------------------------------
extern "C" void kernel_launch(void* const* d_in, const int* in_sizes, int n_in,
                              void* d_out, int out_size, void* d_ws, size_t ws_size,
                              hipStream_t stream) {
  const float* x       = (const float*)d_in[0];
  const float* w1      = (const float*)d_in[1];
  const float* b1      = (const float*)d_in[2];
  const float* prelu_a = (const float*)d_in[3];
  const float* gamma   = (const float*)d_in[4];
  const float* beta    = (const float*)d_in[5];
  const float* w2      = (const float*)d_in[6];
  const float* b2      = (const float*)d_in[7];

  float* z_out = (float*)d_out;
  float* yhat  = z_out + (size_t)8192 * 128;

  char* ws = (char*)d_ws;
  u16* w1t  = (u16*)(ws);                                        // [512][1024]  1 MB
  u16* w2t  = (u16*)(ws + (1u << 20));                           // [128][512]   128 KB
  u16* hact = (u16*)(ws + (1u << 20) + (1u << 17));              // [8192][512]  8 MB
  u16* hln  = (u16*)(ws + (1u << 20) + (1u << 17) + (8u << 20)); // [8192][512]  8 MB
  u16* zn   = (u16*)(ws + (1u << 20) + (1u << 17) + (16u << 20)); // [8192][128] 2 MB

  transpose_both<<<dim3(16, 32, 2), dim3(32, 8), 0, stream>>>(w1, w1t, w2, w2t);
  gemm1_kernel<<<dim3(128, 4), 256, 0, stream>>>(x, w1t, b1, prelu_a, hact);
  ln_kernel<<<2048, 256, 0, stream>>>(hact, gamma, beta, hln);
  gemm2_kernel<<<256, 256, 0, stream>>>(hln, w2t, b2, z_out, zn);
  gram_kernel<<<dim3(64, 64), 256, 0, stream>>>(zn, yhat);
}